// Round 8
// baseline (134.344 us; speedup 1.0000x reference)
//
#include <hip/hip_runtime.h>
#include <hip/hip_bf16.h>
#include <math.h>

// B=16, H=64, W=64, C=64 -> N=4096 pixels/batch, M=1024 pooled cells.
#define NB 16
#define NPIX 4096
#define MPOOL 1024

typedef __attribute__((ext_vector_type(8))) short bf16x8;  // 8 bf16 (4 VGPRs)
typedef __attribute__((ext_vector_type(4))) float f32x4;   // MFMA C/D frag

__device__ inline unsigned short f2bf(float f) {
    __hip_bfloat16 h = __float2bfloat16(f);
    return *reinterpret_cast<unsigned short*>(&h);
}

// Workspace layout (u16 elements from start of ws):
//   wcT_bf  @0       [48*64]   : combined conv weights, TRANSPOSED [col][k].
//                                cols 0-7 theta (pre-scaled by log2e), 8-15 phi, 16-47 g.
//   woT_bf  @3072    [64*32]   : output conv weights TRANSPOSED [co][k].
//   theta_bf@5120    [16*4096*8]
//   phi_bf  @529408  [16*1024*8]
//   gT_bf   @660480  [16*32*1024]

// ---------------- Spectral norm (1 wave per weight) -> bf16 transposed weights ----------------
__device__ inline float wave_sum64(float v) {
    #pragma unroll
    for (int off = 32; off >= 1; off >>= 1) v += __shfl_xor(v, off);
    return v;
}

__global__ void sn_kernel(const float* __restrict__ w_theta, const float* __restrict__ u_theta,
                          const float* __restrict__ w_phi,   const float* __restrict__ u_phi,
                          const float* __restrict__ w_g,     const float* __restrict__ u_g,
                          const float* __restrict__ w_o,     const float* __restrict__ u_o,
                          unsigned short* __restrict__ wcT_bf,
                          unsigned short* __restrict__ woT_bf) {
    const float* w; const float* u; unsigned short* dst; int d, cout;
    switch (blockIdx.x) {
      case 0:  w = w_theta; u = u_theta; dst = wcT_bf;           d = 64; cout = 8;  break;
      case 1:  w = w_phi;   u = u_phi;   dst = wcT_bf + 8 * 64;  d = 64; cout = 8;  break;
      case 2:  w = w_g;     u = u_g;     dst = wcT_bf + 16 * 64; d = 64; cout = 32; break;
      default: w = w_o;     u = u_o;     dst = woT_bf;           d = 32; cout = 64; break;
    }
    __shared__ float sv[64];
    __shared__ float su2[64];
    const int tid = threadIdx.x;

    float vi = 0.f;
    if (tid < d) for (int j = 0; j < cout; ++j) vi += w[tid * cout + j] * u[j];
    float nn = wave_sum64(vi * vi);
    vi *= 1.0f / (sqrtf(nn) + 1e-12f);
    sv[tid] = vi;
    __syncthreads();

    float u2j = 0.f;
    if (tid < cout) for (int i = 0; i < d; ++i) u2j += w[i * cout + tid] * sv[i];
    float nn2 = wave_sum64(u2j * u2j);
    u2j *= 1.0f / (sqrtf(nn2) + 1e-12f);
    su2[tid] = u2j;
    __syncthreads();

    float ti = 0.f;
    if (tid < d) for (int j = 0; j < cout; ++j) ti += w[tid * cout + j] * su2[j];
    float sig = wave_sum64(vi * ti);
    float inv_sig = 1.0f / sig;
    // theta weight carries log2(e) so attn can use exp2 directly.
    if (blockIdx.x == 0) inv_sig *= 1.4426950408889634f;
    // transposed bf16 store: dst[j][i] = w[i][j]/sigma
    for (int idx = tid; idx < d * cout; idx += 64) {
        const int i = idx / cout, j = idx - i * cout;
        dst[j * d + i] = f2bf(w[idx] * inv_sig);
    }
}

// ---------------- fused conv: theta + (phi,g)+maxpool via MFMA ----------------
// Block = 256 thr = 4 waves; covers one 2-row pixel strip (128 px) of one image.
__global__ __launch_bounds__(256) void conv_all_kernel(const float* __restrict__ x,
                                                       const unsigned short* __restrict__ wcT_bf,
                                                       unsigned short* __restrict__ theta_bf,
                                                       unsigned short* __restrict__ phi_bf,
                                                       unsigned short* __restrict__ gT_bf) {
    __shared__ unsigned short sx[128 * 72];  // x strip bf16, row pad 72
    __shared__ unsigned short sw[48 * 72];   // W^T [col][k], pad 72

    const int tid = threadIdx.x;
    const int b  = blockIdx.x >> 5;
    const int hp = blockIdx.x & 31;          // rows 2hp, 2hp+1
    const int h0 = hp * 2;

    // stage x strip: 8192 floats = 2048 float4 -> 8 iters
    const float4* xb4 = (const float4*)(x + (((size_t)b * NPIX) + h0 * 64) * 64);
    #pragma unroll
    for (int it = 0; it < 8; ++it) {
        const int li = tid + it * 256;
        float4 v = xb4[li];
        const int px = li >> 4, c4 = li & 15;
        unsigned lo = (unsigned)f2bf(v.x) | ((unsigned)f2bf(v.y) << 16);
        unsigned hi = (unsigned)f2bf(v.z) | ((unsigned)f2bf(v.w) << 16);
        uint2 pk; pk.x = lo; pk.y = hi;
        *(uint2*)(&sx[px * 72 + c4 * 4]) = pk;
    }
    for (int idx = tid; idx < 48 * 64; idx += 256) {
        const int col = idx >> 6, k = idx & 63;
        sw[col * 72 + k] = wcT_bf[idx];
    }
    __syncthreads();

    const int w    = tid >> 6;
    const int lane = tid & 63;
    const int quad = lane >> 4;
    const int lcol = lane & 15;
    const int w0   = w * 16;

    bf16x8 a[2][2];
    #pragma unroll
    for (int hh = 0; hh < 2; ++hh)
        #pragma unroll
        for (int kc = 0; kc < 2; ++kc)
            a[hh][kc] = *(const bf16x8*)(sx + (hh * 64 + w0 + lcol) * 72 + kc * 32 + quad * 8);

    f32x4 acc[2][3];
    #pragma unroll
    for (int ct = 0; ct < 3; ++ct) {
        bf16x8 b0 = *(const bf16x8*)(sw + (ct * 16 + lcol) * 72 + 0 * 32 + quad * 8);
        bf16x8 b1 = *(const bf16x8*)(sw + (ct * 16 + lcol) * 72 + 1 * 32 + quad * 8);
        #pragma unroll
        for (int hh = 0; hh < 2; ++hh) {
            f32x4 c = __builtin_amdgcn_mfma_f32_16x16x32_bf16(a[hh][0], b0, (f32x4)0.0f, 0, 0, 0);
            acc[hh][ct] = __builtin_amdgcn_mfma_f32_16x16x32_bf16(a[hh][1], b1, c, 0, 0, 0);
        }
    }

    if (lcol < 8) {
        #pragma unroll
        for (int hh = 0; hh < 2; ++hh) {
            const size_t rowbase = (size_t)b * NPIX + (h0 + hh) * 64 + w0 + quad * 4;
            #pragma unroll
            for (int r = 0; r < 4; ++r)
                theta_bf[(rowbase + r) * 8 + lcol] = f2bf(acc[hh][0][r]);
        }
    }
    const int mcb = hp * 32 + (w0 >> 1) + quad * 2;
    if (lcol >= 8) {
        #pragma unroll
        for (int r2 = 0; r2 < 2; ++r2) {
            float pe = fmaxf(fmaxf(acc[0][0][2 * r2], acc[0][0][2 * r2 + 1]),
                             fmaxf(acc[1][0][2 * r2], acc[1][0][2 * r2 + 1]));
            phi_bf[((size_t)b * MPOOL + mcb + r2) * 8 + (lcol - 8)] = f2bf(pe);
        }
    }
    #pragma unroll
    for (int ct = 1; ct < 3; ++ct) {
        const int cg = (ct - 1) * 16 + lcol;
        #pragma unroll
        for (int r2 = 0; r2 < 2; ++r2) {
            float pe = fmaxf(fmaxf(acc[0][ct][2 * r2], acc[0][ct][2 * r2 + 1]),
                             fmaxf(acc[1][ct][2 * r2], acc[1][ct][2 * r2 + 1]));
            gT_bf[((size_t)b * 32 + cg) * MPOOL + mcb + r2] = f2bf(pe);
        }
    }
}

// ---------------- fused MFMA attention + output conv + residual ----------------
// Block = 512 thr = 8 waves; wave = 16 q rows. Grid = 16 b x 32 qb.
// Single pass, exp2 (log2e folded into theta). QK transposed (A=phi, B=theta):
// lane's C-regs = 4 consecutive m's for fixed q=lcol -> uint2 P stores, per-lane ls.
// phi A-frags read straight from GLOBAL (L1-resident 16 KB/batch, quad-uniform
// address) -- no sphi staging, fewer LDS-pipe ops.
// Epilogue: out-conv A=wo, B=ag -> D[ch][q]; 1/ls folded post-conv.
__global__ __launch_bounds__(512) void attn_kernel(const unsigned short* __restrict__ theta_bf,
                                                   const unsigned short* __restrict__ phi_bf,
                                                   const unsigned short* __restrict__ gT_bf,
                                                   const unsigned short* __restrict__ woT_bf,
                                                   const float* __restrict__ x,
                                                   const float* __restrict__ gamma,
                                                   float* __restrict__ out) {
    __shared__ unsigned short sg[2][32 * 264];   // 33.8 KB: gT tile [32 ch][256 m + 8 pad]
    __shared__ unsigned short sP[8][16 * 72];    // 18.4 KB: per-wave P 16q x 64m, stride 72
    __shared__ unsigned short swo[64 * 40];      // 5.1 KB: woT [64 co][32 k + 8 pad]

    const int tid  = threadIdx.x;
    const int b    = blockIdx.x >> 5;
    const int qb   = blockIdx.x & 31;
    const int w    = tid >> 6;
    const int lane = tid & 63;
    const int quad = lane >> 4;
    const int lcol = lane & 15;

    // stage woT
    for (int idx = tid; idx < 64 * 32; idx += 512) {
        const int n = idx >> 5, k = idx & 31;
        swo[n * 40 + k] = woT_bf[idx];
    }
    // stage gT tile 0
    const unsigned short* gTb = gT_bf + (size_t)b * (32 * MPOOL);
    const int prow = tid >> 4, pseg = tid & 15;
    {
        const float4* src = (const float4*)(gTb + prow * MPOOL + pseg * 16);
        float4 r0 = src[0], r1 = src[1];
        float4* dst = (float4*)(&sg[0][prow * 264 + pseg * 16]);
        dst[0] = r0; dst[1] = r1;
    }
    // theta frag (K=8 real, zero-pad k>=8 -> quads 1-3 zero); used as B operand.
    const int q0w = qb * 128 + w * 16;
    bf16x8 tfrag = (bf16x8)(short)0;
    if (quad == 0)
        tfrag = *(const bf16x8*)(theta_bf + ((size_t)b * NPIX + q0w + lcol) * 8);
    const unsigned short* phib = phi_bf + (size_t)b * (MPOOL * 8);
    __syncthreads();

    f32x4 olo = (f32x4)0.0f, ohi = (f32x4)0.0f;
    float ls = 0.f;
    unsigned short* sPw = sP[w];

    float4 pre0, pre1;
    for (int t = 0; t < 4; ++t) {
        if (t < 3) {
            const float4* src = (const float4*)(gTb + prow * MPOOL + (t + 1) * 256 + pseg * 16);
            pre0 = src[0]; pre1 = src[1];
        }
        const unsigned short* sgb = sg[t & 1];
        for (int cb = 0; cb < 4; ++cb) {
            const int m0 = t * 256 + cb * 64;
            f32x4 s[4];
            #pragma unroll
            for (int sc = 0; sc < 4; ++sc) {
                // phi A-frag from global; same 16B for all quads (k>=8 of B is zero).
                bf16x8 pf = *(const bf16x8*)(phib + (size_t)(m0 + sc * 16 + lcol) * 8);
                // S^T tile: D[row=m (quad*4+r within sc*16)][col=q (lcol)]
                s[sc] = __builtin_amdgcn_mfma_f32_16x16x32_bf16(pf, tfrag, (f32x4)0.0f, 0, 0, 0);
            }
            #pragma unroll
            for (int sc = 0; sc < 4; ++sc) {
                float e0 = exp2f(s[sc][0]);
                float e1 = exp2f(s[sc][1]);
                float e2 = exp2f(s[sc][2]);
                float e3 = exp2f(s[sc][3]);
                ls += (e0 + e1) + (e2 + e3);
                uint2 pk2;
                pk2.x = (unsigned)f2bf(e0) | ((unsigned)f2bf(e1) << 16);
                pk2.y = (unsigned)f2bf(e2) | ((unsigned)f2bf(e3) << 16);
                // P[q=lcol][m-in-chunk = sc*16 + quad*4 .. +3]
                *(uint2*)(sPw + lcol * 72 + sc * 16 + quad * 4) = pk2;
            }
            asm volatile("s_waitcnt lgkmcnt(0)" ::: "memory");
            #pragma unroll
            for (int pkk = 0; pkk < 2; ++pkk) {
                bf16x8 afrag = *(const bf16x8*)(sPw + lcol * 72 + pkk * 32 + quad * 8);
                bf16x8 bg0 = *(const bf16x8*)(sgb + lcol * 264 + cb * 64 + pkk * 32 + quad * 8);
                olo = __builtin_amdgcn_mfma_f32_16x16x32_bf16(afrag, bg0, olo, 0, 0, 0);
                bf16x8 bg1 = *(const bf16x8*)(sgb + (16 + lcol) * 264 + cb * 64 + pkk * 32 + quad * 8);
                ohi = __builtin_amdgcn_mfma_f32_16x16x32_bf16(afrag, bg1, ohi, 0, 0, 0);
            }
        }
        if (t < 3) {
            float4* dst = (float4*)(&sg[(t + 1) & 1][prow * 264 + pseg * 16]);
            dst[0] = pre0; dst[1] = pre1;
        }
        __syncthreads();
    }

    // total softmax denominator for q = lcol: sum over quads (lanes lcol+16k)
    ls += __shfl_xor(ls, 16);
    ls += __shfl_xor(ls, 32);
    const float invq = 1.0f / ls;

    // ag (UNNORMALIZED) -> per-wave LDS round-trip: [q][ch], stride 40
    #pragma unroll
    for (int r = 0; r < 4; ++r) {
        sPw[(quad * 4 + r) * 40 + lcol]      = f2bf(olo[r]);
        sPw[(quad * 4 + r) * 40 + 16 + lcol] = f2bf(ohi[r]);
    }
    asm volatile("s_waitcnt lgkmcnt(0)" ::: "memory");
    bf16x8 agf = *(const bf16x8*)(sPw + lcol * 40 + quad * 8);  // B[k=ch][n=q=lcol]

    const float gmi = gamma[0] * invq;
    const size_t pixbase = ((size_t)b * NPIX + q0w + lcol) * 64;
    #pragma unroll
    for (int ct = 0; ct < 4; ++ct) {
        bf16x8 wa = *(const bf16x8*)(swo + (ct * 16 + lcol) * 40 + quad * 8);  // A[co][k]
        f32x4 oc = __builtin_amdgcn_mfma_f32_16x16x32_bf16(wa, agf, (f32x4)0.0f, 0, 0, 0);
        // oc[r] = channel ct*16 + quad*4 + r at pixel q0w + lcol
        const float4 xv = *(const float4*)(x + pixbase + ct * 16 + quad * 4);
        float4 ov;
        ov.x = xv.x + gmi * oc[0];
        ov.y = xv.y + gmi * oc[1];
        ov.z = xv.z + gmi * oc[2];
        ov.w = xv.w + gmi * oc[3];
        *(float4*)(out + pixbase + ct * 16 + quad * 4) = ov;
    }
}

extern "C" void kernel_launch(void* const* d_in, const int* in_sizes, int n_in,
                              void* d_out, int out_size, void* d_ws, size_t ws_size,
                              hipStream_t stream) {
    const float* x       = (const float*)d_in[0];
    const float* w_theta = (const float*)d_in[1];
    const float* u_theta = (const float*)d_in[2];
    const float* w_phi   = (const float*)d_in[3];
    const float* u_phi   = (const float*)d_in[4];
    const float* w_g     = (const float*)d_in[5];
    const float* u_g     = (const float*)d_in[6];
    const float* w_o     = (const float*)d_in[7];
    const float* u_o     = (const float*)d_in[8];
    const float* gamma   = (const float*)d_in[9];
    float* out = (float*)d_out;

    unsigned short* u16base  = (unsigned short*)d_ws;
    unsigned short* wcT_bf   = u16base;                  // 3072
    unsigned short* woT_bf   = u16base + 3072;           // 2048
    unsigned short* theta_bf = u16base + 5120;           // 524288
    unsigned short* phi_bf   = u16base + 529408;         // 131072
    unsigned short* gT_bf    = u16base + 660480;         // 524288

    sn_kernel<<<4, 64, 0, stream>>>(w_theta, u_theta, w_phi, u_phi, w_g, u_g, w_o, u_o,
                                    wcT_bf, woT_bf);
    conv_all_kernel<<<512, 256, 0, stream>>>(x, wcT_bf, theta_bf, phi_bf, gT_bf);
    attn_kernel<<<512, 512, 0, stream>>>(theta_bf, phi_bf, gT_bf, woT_bf, x, gamma, out);
}

// Round 9
// 125.538 us; speedup vs baseline: 1.0701x; 1.0701x over previous
//
#include <hip/hip_runtime.h>
#include <hip/hip_bf16.h>
#include <math.h>

// B=16, H=64, W=64, C=64 -> N=4096 pixels/batch, M=1024 pooled cells.
#define NB 16
#define NPIX 4096
#define MPOOL 1024

typedef __attribute__((ext_vector_type(8))) short bf16x8;  // 8 bf16 (4 VGPRs)
typedef __attribute__((ext_vector_type(4))) float f32x4;   // MFMA C/D frag

__device__ inline unsigned short f2bf(float f) {
    __hip_bfloat16 h = __float2bfloat16(f);
    return *reinterpret_cast<unsigned short*>(&h);
}

// Packed f32x2 -> bf16x2 in one dword: low 16 = bf16(a), high 16 = bf16(b).
// gfx950 has v_cvt_pk_bf16_f32; fallback = round-half-up (+0x8000) + v_perm pack.
#if defined(__has_builtin)
#if __has_builtin(__builtin_amdgcn_cvt_pk_bf16_f32)
#define HAVE_PK_BF16 1
#endif
#endif
__device__ inline unsigned pack_bf16(float a, float b) {
#ifdef HAVE_PK_BF16
    typedef __bf16 bf16v2 __attribute__((ext_vector_type(2)));
    bf16v2 v = __builtin_amdgcn_cvt_pk_bf16_f32(a, b);
    unsigned u;
    __builtin_memcpy(&u, &v, 4);
    return u;
#else
    unsigned ua = __float_as_uint(a) + 0x8000u;
    unsigned ub = __float_as_uint(b) + 0x8000u;
    // sel 0x03020706: D.b0=ua.b2, D.b1=ua.b3 (low16=bf16(a)); D.b2=ub.b2, D.b3=ub.b3
    return __builtin_amdgcn_perm(ua, ub, 0x03020706u);
#endif
}

// Workspace layout (u16 elements from start of ws):
//   wcT_bf  @0       [48*64]   : combined conv weights, TRANSPOSED [col][k].
//                                cols 0-7 theta (pre-scaled by log2e), 8-15 phi, 16-47 g.
//   woT_bf  @3072    [64*32]   : output conv weights TRANSPOSED [co][k].
//   theta_bf@5120    [16*4096*8]
//   phi_bf  @529408  [16*1024*8]
//   gT_bf   @660480  [16*32*1024]

// ---------------- Spectral norm (1 wave per weight) -> bf16 transposed weights ----------------
__device__ inline float wave_sum64(float v) {
    #pragma unroll
    for (int off = 32; off >= 1; off >>= 1) v += __shfl_xor(v, off);
    return v;
}

__global__ void sn_kernel(const float* __restrict__ w_theta, const float* __restrict__ u_theta,
                          const float* __restrict__ w_phi,   const float* __restrict__ u_phi,
                          const float* __restrict__ w_g,     const float* __restrict__ u_g,
                          const float* __restrict__ w_o,     const float* __restrict__ u_o,
                          unsigned short* __restrict__ wcT_bf,
                          unsigned short* __restrict__ woT_bf) {
    const float* w; const float* u; unsigned short* dst; int d, cout;
    switch (blockIdx.x) {
      case 0:  w = w_theta; u = u_theta; dst = wcT_bf;           d = 64; cout = 8;  break;
      case 1:  w = w_phi;   u = u_phi;   dst = wcT_bf + 8 * 64;  d = 64; cout = 8;  break;
      case 2:  w = w_g;     u = u_g;     dst = wcT_bf + 16 * 64; d = 64; cout = 32; break;
      default: w = w_o;     u = u_o;     dst = woT_bf;           d = 32; cout = 64; break;
    }
    __shared__ float sv[64];
    __shared__ float su2[64];
    const int tid = threadIdx.x;

    float vi = 0.f;
    if (tid < d) for (int j = 0; j < cout; ++j) vi += w[tid * cout + j] * u[j];
    float nn = wave_sum64(vi * vi);
    vi *= 1.0f / (sqrtf(nn) + 1e-12f);
    sv[tid] = vi;
    __syncthreads();

    float u2j = 0.f;
    if (tid < cout) for (int i = 0; i < d; ++i) u2j += w[i * cout + tid] * sv[i];
    float nn2 = wave_sum64(u2j * u2j);
    u2j *= 1.0f / (sqrtf(nn2) + 1e-12f);
    su2[tid] = u2j;
    __syncthreads();

    float ti = 0.f;
    if (tid < d) for (int j = 0; j < cout; ++j) ti += w[tid * cout + j] * su2[j];
    float sig = wave_sum64(vi * ti);
    float inv_sig = 1.0f / sig;
    // theta weight carries log2(e) so attn can use exp2 directly.
    if (blockIdx.x == 0) inv_sig *= 1.4426950408889634f;
    // transposed bf16 store: dst[j][i] = w[i][j]/sigma
    for (int idx = tid; idx < d * cout; idx += 64) {
        const int i = idx / cout, j = idx - i * cout;
        dst[j * d + i] = f2bf(w[idx] * inv_sig);
    }
}

// ---------------- fused conv: theta + (phi,g)+maxpool via MFMA ----------------
// Block = 256 thr = 4 waves; covers one 2-row pixel strip (128 px) of one image.
__global__ __launch_bounds__(256) void conv_all_kernel(const float* __restrict__ x,
                                                       const unsigned short* __restrict__ wcT_bf,
                                                       unsigned short* __restrict__ theta_bf,
                                                       unsigned short* __restrict__ phi_bf,
                                                       unsigned short* __restrict__ gT_bf) {
    __shared__ unsigned short sx[128 * 72];  // x strip bf16, row pad 72
    __shared__ unsigned short sw[48 * 72];   // W^T [col][k], pad 72

    const int tid = threadIdx.x;
    const int b  = blockIdx.x >> 5;
    const int hp = blockIdx.x & 31;          // rows 2hp, 2hp+1
    const int h0 = hp * 2;

    // stage x strip: 8192 floats = 2048 float4 -> 8 iters
    const float4* xb4 = (const float4*)(x + (((size_t)b * NPIX) + h0 * 64) * 64);
    #pragma unroll
    for (int it = 0; it < 8; ++it) {
        const int li = tid + it * 256;
        float4 v = xb4[li];
        const int px = li >> 4, c4 = li & 15;
        uint2 pk;
        pk.x = pack_bf16(v.x, v.y);
        pk.y = pack_bf16(v.z, v.w);
        *(uint2*)(&sx[px * 72 + c4 * 4]) = pk;
    }
    for (int idx = tid; idx < 48 * 64; idx += 256) {
        const int col = idx >> 6, k = idx & 63;
        sw[col * 72 + k] = wcT_bf[idx];
    }
    __syncthreads();

    const int w    = tid >> 6;
    const int lane = tid & 63;
    const int quad = lane >> 4;
    const int lcol = lane & 15;
    const int w0   = w * 16;

    bf16x8 a[2][2];
    #pragma unroll
    for (int hh = 0; hh < 2; ++hh)
        #pragma unroll
        for (int kc = 0; kc < 2; ++kc)
            a[hh][kc] = *(const bf16x8*)(sx + (hh * 64 + w0 + lcol) * 72 + kc * 32 + quad * 8);

    f32x4 acc[2][3];
    #pragma unroll
    for (int ct = 0; ct < 3; ++ct) {
        bf16x8 b0 = *(const bf16x8*)(sw + (ct * 16 + lcol) * 72 + 0 * 32 + quad * 8);
        bf16x8 b1 = *(const bf16x8*)(sw + (ct * 16 + lcol) * 72 + 1 * 32 + quad * 8);
        #pragma unroll
        for (int hh = 0; hh < 2; ++hh) {
            f32x4 c = __builtin_amdgcn_mfma_f32_16x16x32_bf16(a[hh][0], b0, (f32x4)0.0f, 0, 0, 0);
            acc[hh][ct] = __builtin_amdgcn_mfma_f32_16x16x32_bf16(a[hh][1], b1, c, 0, 0, 0);
        }
    }

    if (lcol < 8) {
        #pragma unroll
        for (int hh = 0; hh < 2; ++hh) {
            const size_t rowbase = (size_t)b * NPIX + (h0 + hh) * 64 + w0 + quad * 4;
            #pragma unroll
            for (int r = 0; r < 4; ++r)
                theta_bf[(rowbase + r) * 8 + lcol] = f2bf(acc[hh][0][r]);
        }
    }
    const int mcb = hp * 32 + (w0 >> 1) + quad * 2;
    if (lcol >= 8) {
        #pragma unroll
        for (int r2 = 0; r2 < 2; ++r2) {
            float pe = fmaxf(fmaxf(acc[0][0][2 * r2], acc[0][0][2 * r2 + 1]),
                             fmaxf(acc[1][0][2 * r2], acc[1][0][2 * r2 + 1]));
            phi_bf[((size_t)b * MPOOL + mcb + r2) * 8 + (lcol - 8)] = f2bf(pe);
        }
    }
    #pragma unroll
    for (int ct = 1; ct < 3; ++ct) {
        const int cg = (ct - 1) * 16 + lcol;
        #pragma unroll
        for (int r2 = 0; r2 < 2; ++r2) {
            float pe = fmaxf(fmaxf(acc[0][ct][2 * r2], acc[0][ct][2 * r2 + 1]),
                             fmaxf(acc[1][ct][2 * r2], acc[1][ct][2 * r2 + 1]));
            gT_bf[((size_t)b * 32 + cg) * MPOOL + mcb + r2] = f2bf(pe);
        }
    }
}

// ---------------- fused MFMA attention + output conv + residual ----------------
// Block = 512 thr = 8 waves; wave = 16 q rows. Grid = 16 b x 32 qb.
// Single pass, exp2 (log2e folded into theta). QK transposed (A=phi from LDS,
// B=theta): lane's C-regs = 4 consecutive m's for fixed q=lcol -> uint2 P stores
// (packed cvt), per-lane ls. Epilogue: out-conv A=wo, B=ag -> D[ch][q]; 1/ls
// folded post-conv.
__global__ __launch_bounds__(512) void attn_kernel(const unsigned short* __restrict__ theta_bf,
                                                   const unsigned short* __restrict__ phi_bf,
                                                   const unsigned short* __restrict__ gT_bf,
                                                   const unsigned short* __restrict__ woT_bf,
                                                   const float* __restrict__ x,
                                                   const float* __restrict__ gamma,
                                                   float* __restrict__ out) {
    __shared__ unsigned short sphi[MPOOL * 8];   // 16 KB: phi[b] rows of 8 bf16
    __shared__ unsigned short sg[2][32 * 264];   // 33.8 KB: gT tile [32 ch][256 m + 8 pad]
    __shared__ unsigned short sP[8][16 * 72];    // 18.4 KB: per-wave P 16q x 64m, stride 72
    __shared__ unsigned short swo[64 * 40];      // 5.1 KB: woT [64 co][32 k + 8 pad]

    const int tid  = threadIdx.x;
    const int b    = blockIdx.x >> 5;
    const int qb   = blockIdx.x & 31;
    const int w    = tid >> 6;
    const int lane = tid & 63;
    const int quad = lane >> 4;
    const int lcol = lane & 15;

    // stage phi[b] (16 KB)
    {
        const float4* src = (const float4*)(phi_bf + (size_t)b * (MPOOL * 8));
        float4* dst = (float4*)sphi;
        dst[2 * tid]     = src[2 * tid];
        dst[2 * tid + 1] = src[2 * tid + 1];
    }
    // stage woT
    for (int idx = tid; idx < 64 * 32; idx += 512) {
        const int n = idx >> 5, k = idx & 31;
        swo[n * 40 + k] = woT_bf[idx];
    }
    // stage gT tile 0
    const unsigned short* gTb = gT_bf + (size_t)b * (32 * MPOOL);
    const int prow = tid >> 4, pseg = tid & 15;
    {
        const float4* src = (const float4*)(gTb + prow * MPOOL + pseg * 16);
        float4 r0 = src[0], r1 = src[1];
        float4* dst = (float4*)(&sg[0][prow * 264 + pseg * 16]);
        dst[0] = r0; dst[1] = r1;
    }
    // theta frag (K=8 real, zero-pad k>=8 -> quads 1-3 zero); used as B operand.
    const int q0w = qb * 128 + w * 16;
    bf16x8 tfrag = (bf16x8)(short)0;
    if (quad == 0)
        tfrag = *(const bf16x8*)(theta_bf + ((size_t)b * NPIX + q0w + lcol) * 8);
    __syncthreads();

    f32x4 olo = (f32x4)0.0f, ohi = (f32x4)0.0f;
    float ls = 0.f;
    unsigned short* sPw = sP[w];

    float4 pre0, pre1;
    for (int t = 0; t < 4; ++t) {
        if (t < 3) {
            const float4* src = (const float4*)(gTb + prow * MPOOL + (t + 1) * 256 + pseg * 16);
            pre0 = src[0]; pre1 = src[1];
        }
        const unsigned short* sgb = sg[t & 1];
        for (int cb = 0; cb < 4; ++cb) {
            const int m0 = t * 256 + cb * 64;
            f32x4 s[4];
            #pragma unroll
            for (int sc = 0; sc < 4; ++sc) {
                bf16x8 pf = *(const bf16x8*)(sphi + (size_t)(m0 + sc * 16 + lcol) * 8);
                // S^T tile: D[row=m (quad*4+r within sc*16)][col=q (lcol)]
                s[sc] = __builtin_amdgcn_mfma_f32_16x16x32_bf16(pf, tfrag, (f32x4)0.0f, 0, 0, 0);
            }
            #pragma unroll
            for (int sc = 0; sc < 4; ++sc) {
                float e0 = exp2f(s[sc][0]);
                float e1 = exp2f(s[sc][1]);
                float e2 = exp2f(s[sc][2]);
                float e3 = exp2f(s[sc][3]);
                ls += (e0 + e1) + (e2 + e3);
                uint2 pk2;
                pk2.x = pack_bf16(e0, e1);
                pk2.y = pack_bf16(e2, e3);
                // P[q=lcol][m-in-chunk = sc*16 + quad*4 .. +3]
                *(uint2*)(sPw + lcol * 72 + sc * 16 + quad * 4) = pk2;
            }
            asm volatile("s_waitcnt lgkmcnt(0)" ::: "memory");
            #pragma unroll
            for (int pkk = 0; pkk < 2; ++pkk) {
                bf16x8 afrag = *(const bf16x8*)(sPw + lcol * 72 + pkk * 32 + quad * 8);
                bf16x8 bg0 = *(const bf16x8*)(sgb + lcol * 264 + cb * 64 + pkk * 32 + quad * 8);
                olo = __builtin_amdgcn_mfma_f32_16x16x32_bf16(afrag, bg0, olo, 0, 0, 0);
                bf16x8 bg1 = *(const bf16x8*)(sgb + (16 + lcol) * 264 + cb * 64 + pkk * 32 + quad * 8);
                ohi = __builtin_amdgcn_mfma_f32_16x16x32_bf16(afrag, bg1, ohi, 0, 0, 0);
            }
        }
        if (t < 3) {
            float4* dst = (float4*)(&sg[(t + 1) & 1][prow * 264 + pseg * 16]);
            dst[0] = pre0; dst[1] = pre1;
        }
        __syncthreads();
    }

    // total softmax denominator for q = lcol: sum over quads (lanes lcol+16k)
    ls += __shfl_xor(ls, 16);
    ls += __shfl_xor(ls, 32);
    const float invq = 1.0f / ls;

    // ag (UNNORMALIZED) -> per-wave LDS round-trip: [q][ch], stride 40
    #pragma unroll
    for (int r = 0; r < 4; ++r) {
        sPw[(quad * 4 + r) * 40 + lcol]      = f2bf(olo[r]);
        sPw[(quad * 4 + r) * 40 + 16 + lcol] = f2bf(ohi[r]);
    }
    asm volatile("s_waitcnt lgkmcnt(0)" ::: "memory");
    bf16x8 agf = *(const bf16x8*)(sPw + lcol * 40 + quad * 8);  // B[k=ch][n=q=lcol]

    const float gmi = gamma[0] * invq;
    const size_t pixbase = ((size_t)b * NPIX + q0w + lcol) * 64;
    #pragma unroll
    for (int ct = 0; ct < 4; ++ct) {
        bf16x8 wa = *(const bf16x8*)(swo + (ct * 16 + lcol) * 40 + quad * 8);  // A[co][k]
        f32x4 oc = __builtin_amdgcn_mfma_f32_16x16x32_bf16(wa, agf, (f32x4)0.0f, 0, 0, 0);
        // oc[r] = channel ct*16 + quad*4 + r at pixel q0w + lcol
        const float4 xv = *(const float4*)(x + pixbase + ct * 16 + quad * 4);
        float4 ov;
        ov.x = xv.x + gmi * oc[0];
        ov.y = xv.y + gmi * oc[1];
        ov.z = xv.z + gmi * oc[2];
        ov.w = xv.w + gmi * oc[3];
        *(float4*)(out + pixbase + ct * 16 + quad * 4) = ov;
    }
}

extern "C" void kernel_launch(void* const* d_in, const int* in_sizes, int n_in,
                              void* d_out, int out_size, void* d_ws, size_t ws_size,
                              hipStream_t stream) {
    const float* x       = (const float*)d_in[0];
    const float* w_theta = (const float*)d_in[1];
    const float* u_theta = (const float*)d_in[2];
    const float* w_phi   = (const float*)d_in[3];
    const float* u_phi   = (const float*)d_in[4];
    const float* w_g     = (const float*)d_in[5];
    const float* u_g     = (const float*)d_in[6];
    const float* w_o     = (const float*)d_in[7];
    const float* u_o     = (const float*)d_in[8];
    const float* gamma   = (const float*)d_in[9];
    float* out = (float*)d_out;

    unsigned short* u16base  = (unsigned short*)d_ws;
    unsigned short* wcT_bf   = u16base;                  // 3072
    unsigned short* woT_bf   = u16base + 3072;           // 2048
    unsigned short* theta_bf = u16base + 5120;           // 524288
    unsigned short* phi_bf   = u16base + 529408;         // 131072
    unsigned short* gT_bf    = u16base + 660480;         // 524288

    sn_kernel<<<4, 64, 0, stream>>>(w_theta, u_theta, w_phi, u_phi, w_g, u_g, w_o, u_o,
                                    wcT_bf, woT_bf);
    conv_all_kernel<<<512, 256, 0, stream>>>(x, wcT_bf, theta_bf, phi_bf, gT_bf);
    attn_kernel<<<512, 512, 0, stream>>>(theta_bf, phi_bf, gT_bf, woT_bf, x, gamma, out);
}

// Round 11
// 120.095 us; speedup vs baseline: 1.1186x; 1.0453x over previous
//
#include <hip/hip_runtime.h>
#include <hip/hip_bf16.h>
#include <math.h>

// B=16, H=64, W=64, C=64 -> N=4096 pixels/batch, M=1024 pooled cells.
#define NB 16
#define NPIX 4096
#define MPOOL 1024

typedef __attribute__((ext_vector_type(8))) short bf16x8;  // 8 bf16 (4 VGPRs)
typedef __attribute__((ext_vector_type(4))) float f32x4;   // MFMA C/D frag

__device__ inline unsigned short f2bf(float f) {
    __hip_bfloat16 h = __float2bfloat16(f);
    return *reinterpret_cast<unsigned short*>(&h);
}

// Packed f32x2 -> bf16x2 in one dword: low 16 = bf16(a), high 16 = bf16(b).
#if defined(__has_builtin)
#if __has_builtin(__builtin_amdgcn_cvt_pk_bf16_f32)
#define HAVE_PK_BF16 1
#endif
#endif
__device__ inline unsigned pack_bf16(float a, float b) {
#ifdef HAVE_PK_BF16
    typedef __bf16 bf16v2 __attribute__((ext_vector_type(2)));
    bf16v2 v = __builtin_amdgcn_cvt_pk_bf16_f32(a, b);
    unsigned u;
    __builtin_memcpy(&u, &v, 4);
    return u;
#else
    unsigned ua = __float_as_uint(a) + 0x8000u;
    unsigned ub = __float_as_uint(b) + 0x8000u;
    return __builtin_amdgcn_perm(ua, ub, 0x03020706u);
#endif
}

// Workspace layout (u16 elements from start of ws):
//   wcT_bf  @0       [48*64]   : combined conv weights, TRANSPOSED [col][k].
//                                cols 0-7 theta, 8-15 phi, 16-47 g.
//   woT_bf  @3072    [64*32]   : output conv weights TRANSPOSED [co][k].
//   theta_bf@5120    [16*4096*8]
//   phi_bf  @529408  [16*1024*8]
//   gT_bf   @660480  [16*32*1024]

// ---------------- Spectral norm (1 wave per weight) -> bf16 transposed weights ----------------
__device__ inline float wave_sum64(float v) {
    #pragma unroll
    for (int off = 32; off >= 1; off >>= 1) v += __shfl_xor(v, off);
    return v;
}

__global__ void sn_kernel(const float* __restrict__ w_theta, const float* __restrict__ u_theta,
                          const float* __restrict__ w_phi,   const float* __restrict__ u_phi,
                          const float* __restrict__ w_g,     const float* __restrict__ u_g,
                          const float* __restrict__ w_o,     const float* __restrict__ u_o,
                          unsigned short* __restrict__ wcT_bf,
                          unsigned short* __restrict__ woT_bf) {
    const float* w; const float* u; unsigned short* dst; int d, cout;
    switch (blockIdx.x) {
      case 0:  w = w_theta; u = u_theta; dst = wcT_bf;           d = 64; cout = 8;  break;
      case 1:  w = w_phi;   u = u_phi;   dst = wcT_bf + 8 * 64;  d = 64; cout = 8;  break;
      case 2:  w = w_g;     u = u_g;     dst = wcT_bf + 16 * 64; d = 64; cout = 32; break;
      default: w = w_o;     u = u_o;     dst = woT_bf;           d = 32; cout = 64; break;
    }
    __shared__ float sv[64];
    __shared__ float su2[64];
    const int tid = threadIdx.x;

    float vi = 0.f;
    if (tid < d) for (int j = 0; j < cout; ++j) vi += w[tid * cout + j] * u[j];
    float nn = wave_sum64(vi * vi);
    vi *= 1.0f / (sqrtf(nn) + 1e-12f);
    sv[tid] = vi;
    __syncthreads();

    float u2j = 0.f;
    if (tid < cout) for (int i = 0; i < d; ++i) u2j += w[i * cout + tid] * sv[i];
    float nn2 = wave_sum64(u2j * u2j);
    u2j *= 1.0f / (sqrtf(nn2) + 1e-12f);
    su2[tid] = u2j;
    __syncthreads();

    float ti = 0.f;
    if (tid < d) for (int j = 0; j < cout; ++j) ti += w[tid * cout + j] * su2[j];
    float sig = wave_sum64(vi * ti);
    const float inv_sig = 1.0f / sig;
    // transposed bf16 store: dst[j][i] = w[i][j]/sigma
    for (int idx = tid; idx < d * cout; idx += 64) {
        const int i = idx / cout, j = idx - i * cout;
        dst[j * d + i] = f2bf(w[idx] * inv_sig);
    }
}

// ---------------- fused conv: theta + (phi,g)+maxpool via MFMA ----------------
// Block = 256 thr = 4 waves; covers one 2-row pixel strip (128 px) of one image.
__global__ __launch_bounds__(256) void conv_all_kernel(const float* __restrict__ x,
                                                       const unsigned short* __restrict__ wcT_bf,
                                                       unsigned short* __restrict__ theta_bf,
                                                       unsigned short* __restrict__ phi_bf,
                                                       unsigned short* __restrict__ gT_bf) {
    __shared__ unsigned short sx[128 * 72];  // x strip bf16, row pad 72
    __shared__ unsigned short sw[48 * 72];   // W^T [col][k], pad 72

    const int tid = threadIdx.x;
    const int b  = blockIdx.x >> 5;
    const int hp = blockIdx.x & 31;          // rows 2hp, 2hp+1
    const int h0 = hp * 2;

    // stage x strip: 8192 floats = 2048 float4 -> 8 iters
    const float4* xb4 = (const float4*)(x + (((size_t)b * NPIX) + h0 * 64) * 64);
    #pragma unroll
    for (int it = 0; it < 8; ++it) {
        const int li = tid + it * 256;
        float4 v = xb4[li];
        const int px = li >> 4, c4 = li & 15;
        uint2 pk;
        pk.x = pack_bf16(v.x, v.y);
        pk.y = pack_bf16(v.z, v.w);
        *(uint2*)(&sx[px * 72 + c4 * 4]) = pk;
    }
    for (int idx = tid; idx < 48 * 64; idx += 256) {
        const int col = idx >> 6, k = idx & 63;
        sw[col * 72 + k] = wcT_bf[idx];
    }
    __syncthreads();

    const int w    = tid >> 6;
    const int lane = tid & 63;
    const int quad = lane >> 4;
    const int lcol = lane & 15;
    const int w0   = w * 16;

    bf16x8 a[2][2];
    #pragma unroll
    for (int hh = 0; hh < 2; ++hh)
        #pragma unroll
        for (int kc = 0; kc < 2; ++kc)
            a[hh][kc] = *(const bf16x8*)(sx + (hh * 64 + w0 + lcol) * 72 + kc * 32 + quad * 8);

    f32x4 acc[2][3];
    #pragma unroll
    for (int ct = 0; ct < 3; ++ct) {
        bf16x8 b0 = *(const bf16x8*)(sw + (ct * 16 + lcol) * 72 + 0 * 32 + quad * 8);
        bf16x8 b1 = *(const bf16x8*)(sw + (ct * 16 + lcol) * 72 + 1 * 32 + quad * 8);
        #pragma unroll
        for (int hh = 0; hh < 2; ++hh) {
            f32x4 c = __builtin_amdgcn_mfma_f32_16x16x32_bf16(a[hh][0], b0, (f32x4)0.0f, 0, 0, 0);
            acc[hh][ct] = __builtin_amdgcn_mfma_f32_16x16x32_bf16(a[hh][1], b1, c, 0, 0, 0);
        }
    }

    if (lcol < 8) {
        #pragma unroll
        for (int hh = 0; hh < 2; ++hh) {
            const size_t rowbase = (size_t)b * NPIX + (h0 + hh) * 64 + w0 + quad * 4;
            #pragma unroll
            for (int r = 0; r < 4; ++r)
                theta_bf[(rowbase + r) * 8 + lcol] = f2bf(acc[hh][0][r]);
        }
    }
    const int mcb = hp * 32 + (w0 >> 1) + quad * 2;
    if (lcol >= 8) {
        #pragma unroll
        for (int r2 = 0; r2 < 2; ++r2) {
            float pe = fmaxf(fmaxf(acc[0][0][2 * r2], acc[0][0][2 * r2 + 1]),
                             fmaxf(acc[1][0][2 * r2], acc[1][0][2 * r2 + 1]));
            phi_bf[((size_t)b * MPOOL + mcb + r2) * 8 + (lcol - 8)] = f2bf(pe);
        }
    }
    #pragma unroll
    for (int ct = 1; ct < 3; ++ct) {
        const int cg = (ct - 1) * 16 + lcol;
        #pragma unroll
        for (int r2 = 0; r2 < 2; ++r2) {
            float pe = fmaxf(fmaxf(acc[0][ct][2 * r2], acc[0][ct][2 * r2 + 1]),
                             fmaxf(acc[1][ct][2 * r2], acc[1][ct][2 * r2 + 1]));
            gT_bf[((size_t)b * 32 + cg) * MPOOL + mcb + r2] = f2bf(pe);
        }
    }
}

// ---------------- fused MFMA attention + output conv + residual ----------------
// Block = 512 thr = 8 waves; wave = 16 q rows. Grid = 16 b x 32 qb.
// Single pass (no max subtraction: scores ~N(0,2), max ~11 << 88, fp32 exp safe).
// QK computed TRANSPOSED (A=phi, B=theta): lane's C-regs = 4 consecutive m's for
// fixed q=lcol -> uint2 P stores, per-lane ls.
// Epilogue: out-conv with A=wo, B=ag -> D[ch][q], float4 residual stores;
// softmax 1/ls folded post-conv (per-q scaling commutes with channel conv).
__global__ __launch_bounds__(512) void attn_kernel(const unsigned short* __restrict__ theta_bf,
                                                   const unsigned short* __restrict__ phi_bf,
                                                   const unsigned short* __restrict__ gT_bf,
                                                   const unsigned short* __restrict__ woT_bf,
                                                   const float* __restrict__ x,
                                                   const float* __restrict__ gamma,
                                                   float* __restrict__ out) {
    __shared__ unsigned short sphi[MPOOL * 8];   // 16 KB
    __shared__ unsigned short sg[2][32 * 264];   // 33.8 KB: gT tile [32 ch][256 m + 8 pad]
    __shared__ unsigned short sP[8][16 * 72];    // 18.4 KB: per-wave P 16q x 64m, stride 72
    __shared__ unsigned short swo[64 * 40];      // 5.1 KB: woT [64 co][32 k + 8 pad]

    const int tid  = threadIdx.x;
    const int b    = blockIdx.x >> 5;
    const int qb   = blockIdx.x & 31;
    const int w    = tid >> 6;
    const int lane = tid & 63;
    const int quad = lane >> 4;
    const int lcol = lane & 15;

    // stage phi[b] (16 KB)
    {
        const float4* src = (const float4*)(phi_bf + (size_t)b * (MPOOL * 8));
        float4* dst = (float4*)sphi;
        dst[2 * tid]     = src[2 * tid];
        dst[2 * tid + 1] = src[2 * tid + 1];
    }
    // stage woT
    for (int idx = tid; idx < 64 * 32; idx += 512) {
        const int n = idx >> 5, k = idx & 31;
        swo[n * 40 + k] = woT_bf[idx];
    }
    // stage gT tile 0
    const unsigned short* gTb = gT_bf + (size_t)b * (32 * MPOOL);
    const int prow = tid >> 4, pseg = tid & 15;
    {
        const float4* src = (const float4*)(gTb + prow * MPOOL + pseg * 16);
        float4 r0 = src[0], r1 = src[1];
        float4* dst = (float4*)(&sg[0][prow * 264 + pseg * 16]);
        dst[0] = r0; dst[1] = r1;
    }
    // theta frag (K=8 real, zero-pad k>=8 -> quads 1-3 zero); used as B operand.
    const int q0w = qb * 128 + w * 16;
    bf16x8 tfrag = (bf16x8)(short)0;
    if (quad == 0)
        tfrag = *(const bf16x8*)(theta_bf + ((size_t)b * NPIX + q0w + lcol) * 8);
    __syncthreads();

    f32x4 olo = (f32x4)0.0f, ohi = (f32x4)0.0f;
    float ls = 0.f;
    unsigned short* sPw = sP[w];

    float4 pre0, pre1;
    for (int t = 0; t < 4; ++t) {
        if (t < 3) {
            const float4* src = (const float4*)(gTb + prow * MPOOL + (t + 1) * 256 + pseg * 16);
            pre0 = src[0]; pre1 = src[1];
        }
        const unsigned short* sgb = sg[t & 1];
        for (int cb = 0; cb < 4; ++cb) {
            const int m0 = t * 256 + cb * 64;
            f32x4 s[4];
            #pragma unroll
            for (int sc = 0; sc < 4; ++sc) {
                bf16x8 pf = *(const bf16x8*)(sphi + (size_t)(m0 + sc * 16 + lcol) * 8);
                // S^T tile: D[row=m (quad*4+r within sc*16)][col=q (lcol)]
                s[sc] = __builtin_amdgcn_mfma_f32_16x16x32_bf16(pf, tfrag, (f32x4)0.0f, 0, 0, 0);
            }
            #pragma unroll
            for (int sc = 0; sc < 4; ++sc) {
                float e0 = __expf(s[sc][0]);
                float e1 = __expf(s[sc][1]);
                float e2 = __expf(s[sc][2]);
                float e3 = __expf(s[sc][3]);
                ls += (e0 + e1) + (e2 + e3);
                uint2 pk2;
                pk2.x = (unsigned)f2bf(e0) | ((unsigned)f2bf(e1) << 16);
                pk2.y = (unsigned)f2bf(e2) | ((unsigned)f2bf(e3) << 16);
                // P[q=lcol][m-in-chunk = sc*16 + quad*4 .. +3]
                *(uint2*)(sPw + lcol * 72 + sc * 16 + quad * 4) = pk2;
            }
            asm volatile("s_waitcnt lgkmcnt(0)" ::: "memory");
            #pragma unroll
            for (int pkk = 0; pkk < 2; ++pkk) {
                bf16x8 afrag = *(const bf16x8*)(sPw + lcol * 72 + pkk * 32 + quad * 8);
                bf16x8 bg0 = *(const bf16x8*)(sgb + lcol * 264 + cb * 64 + pkk * 32 + quad * 8);
                olo = __builtin_amdgcn_mfma_f32_16x16x32_bf16(afrag, bg0, olo, 0, 0, 0);
                bf16x8 bg1 = *(const bf16x8*)(sgb + (16 + lcol) * 264 + cb * 64 + pkk * 32 + quad * 8);
                ohi = __builtin_amdgcn_mfma_f32_16x16x32_bf16(afrag, bg1, ohi, 0, 0, 0);
            }
        }
        if (t < 3) {
            float4* dst = (float4*)(&sg[(t + 1) & 1][prow * 264 + pseg * 16]);
            dst[0] = pre0; dst[1] = pre1;
        }
        __syncthreads();
    }

    // total softmax denominator for q = lcol: sum over quads (lanes lcol+16k)
    ls += __shfl_xor(ls, 16);
    ls += __shfl_xor(ls, 32);
    const float invq = 1.0f / ls;

    // ag (UNNORMALIZED) -> per-wave LDS round-trip: [q][ch], stride 40
    #pragma unroll
    for (int r = 0; r < 4; ++r) {
        sPw[(quad * 4 + r) * 40 + lcol]      = f2bf(olo[r]);
        sPw[(quad * 4 + r) * 40 + 16 + lcol] = f2bf(ohi[r]);
    }
    asm volatile("s_waitcnt lgkmcnt(0)" ::: "memory");
    bf16x8 agf = *(const bf16x8*)(sPw + lcol * 40 + quad * 8);  // B[k=ch][n=q=lcol]

    const float gmi = gamma[0] * invq;
    const size_t pixbase = ((size_t)b * NPIX + q0w + lcol) * 64;
    #pragma unroll
    for (int ct = 0; ct < 4; ++ct) {
        bf16x8 wa = *(const bf16x8*)(swo + (ct * 16 + lcol) * 40 + quad * 8);  // A[co][k]
        f32x4 oc = __builtin_amdgcn_mfma_f32_16x16x32_bf16(wa, agf, (f32x4)0.0f, 0, 0, 0);
        // oc[r] = channel ct*16 + quad*4 + r at pixel q0w + lcol
        const float4 xv = *(const float4*)(x + pixbase + ct * 16 + quad * 4);
        float4 ov;
        ov.x = xv.x + gmi * oc[0];
        ov.y = xv.y + gmi * oc[1];
        ov.z = xv.z + gmi * oc[2];
        ov.w = xv.w + gmi * oc[3];
        *(float4*)(out + pixbase + ct * 16 + quad * 4) = ov;
    }
}

extern "C" void kernel_launch(void* const* d_in, const int* in_sizes, int n_in,
                              void* d_out, int out_size, void* d_ws, size_t ws_size,
                              hipStream_t stream) {
    const float* x       = (const float*)d_in[0];
    const float* w_theta = (const float*)d_in[1];
    const float* u_theta = (const float*)d_in[2];
    const float* w_phi   = (const float*)d_in[3];
    const float* u_phi   = (const float*)d_in[4];
    const float* w_g     = (const float*)d_in[5];
    const float* u_g     = (const float*)d_in[6];
    const float* w_o     = (const float*)d_in[7];
    const float* u_o     = (const float*)d_in[8];
    const float* gamma   = (const float*)d_in[9];
    float* out = (float*)d_out;

    unsigned short* u16base  = (unsigned short*)d_ws;
    unsigned short* wcT_bf   = u16base;                  // 3072
    unsigned short* woT_bf   = u16base + 3072;           // 2048
    unsigned short* theta_bf = u16base + 5120;           // 524288
    unsigned short* phi_bf   = u16base + 529408;         // 131072
    unsigned short* gT_bf    = u16base + 660480;         // 524288

    sn_kernel<<<4, 64, 0, stream>>>(w_theta, u_theta, w_phi, u_phi, w_g, u_g, w_o, u_o,
                                    wcT_bf, woT_bf);
    conv_all_kernel<<<512, 256, 0, stream>>>(x, wcT_bf, theta_bf, phi_bf, gT_bf);
    attn_kernel<<<512, 512, 0, stream>>>(theta_bf, phi_bf, gT_bf, woT_bf, x, gamma, out);
}